// Round 11
// baseline (158.893 us; speedup 1.0000x reference)
//
#include <hip/hip_runtime.h>

// ---------------------------------------------------------------------------
// HilbertAttention: fused cast -> fused {perm-gathered Q-proj | dilation-
// packed KV-proj} (fp16 MFMA, 256^2 8-phase, ONE barrier per phase)
// -> segmented attention -> out-proj.
// B=4, M=4096, D=1024, H=16, hd=64, SEG=128, DIL=2 -> S=32.
// perm = closed-form serpentine (g==64), an involution, row-group-preserving.
// R11: Q-GEMM gathers A rows through hperm (same per-lane gload_lds mechanism
// as the KV path) so qh is stored pre-permuted and attention reads Q linearly.
// cast_all uses nontemporal loads (inputs read exactly once).
// ---------------------------------------------------------------------------

typedef _Float16 f16x8 __attribute__((ext_vector_type(8)));
typedef _Float16 f16x4 __attribute__((ext_vector_type(4)));
typedef float f32x4 __attribute__((ext_vector_type(4)));

__device__ __forceinline__ int hperm(int i) {
  int r = i >> 6, c = i & 63;
  return (r << 6) | ((r & 1) ? (63 - c) : c);
}
// Q-space row mp in [0,16384): apply hperm within the 4096-row batch block.
// hperm preserves 64-row groups and b-offsets are 4096-aligned, so:
__device__ __forceinline__ int qrow_gather(int mp) {
  return (mp & ~63) | (((mp >> 6) & 1) ? (63 - (mp & 63)) : (mp & 63));
}
// A'-row m' -> x-row for KV gather: m' = b*2048+s*64+j -> b*4096+hperm(s*128+2j)
__device__ __forceinline__ int arow_gather(int mp) {
  int b = mp >> 11, i = mp & 2047;
  int s = i >> 6, j = i & 63;
  return b * 4096 + hperm(s * 128 + 2 * j);
}
__device__ __forceinline__ void gload_lds16(const _Float16* g, _Float16* l) {
  __builtin_amdgcn_global_load_lds(
      (const __attribute__((address_space(1))) void*)g,
      (__attribute__((address_space(3))) void*)l, 16, 0, 0);
}

// -------------------- fused cast fp32 -> fp16 (grid-stride, NT loads) ------
__global__ __launch_bounds__(256) void cast_all(
    const float* __restrict__ x, _Float16* __restrict__ xh,
    const float* __restrict__ wq, _Float16* __restrict__ wqh,
    const float* __restrict__ wo, _Float16* __restrict__ woh) {
  for (int i = blockIdx.x * 256 + threadIdx.x; i < 5242880; i += 256 * 2048) {
    const float* s;
    _Float16* d;
    int j;
    if (i < 4194304) {
      s = x; d = xh; j = i;
    } else if (i < 4980736) {
      s = wq; d = wqh; j = i - 4194304;
    } else {
      s = wo; d = woh; j = i - 4980736;
    }
    f32x4 v = __builtin_nontemporal_load((const f32x4*)s + j);
    f16x4 o;
    o[0] = (_Float16)v[0];
    o[1] = (_Float16)v[1];
    o[2] = (_Float16)v[2];
    o[3] = (_Float16)v[3];
    *(f16x4*)&d[(size_t)j * 4] = o;
  }
}

// ---------------- 256x256 8-phase NT GEMM body: C = A * B^T ----------------
// K=1024 (NK=16), BK=64, 512 thr = 8 waves (2Mx4N), per-wave 128x64 out.
// LDS 128 KiB. Swizzle: 16B-slot XOR ((row&7)<<3 halves).
// Stage slots: P0/P1 = A(k1)->buf1; P2..P5 = B,B,A,A of (k2)->buf0;
// P6/P7 = B(k3)->buf1. vmcnt(4) only at P3/P7 (counted, never 0 in loop).
// Final iteration peeled: stage only A(15); vmcnt(0) at its P3; quadrant
// stores issued right after each quadrant's final MFMA (P4..P7).

#define BAR __builtin_amdgcn_s_barrier()
#define LGKM0                                          \
  do {                                                 \
    asm volatile("s_waitcnt lgkmcnt(0)" ::: "memory"); \
    __builtin_amdgcn_sched_barrier(0);                 \
  } while (0)
#define VM4 asm volatile("s_waitcnt vmcnt(4)" ::: "memory")
#define VM0 asm volatile("s_waitcnt vmcnt(0)" ::: "memory")

#define STG(mat, kt, h, buf)                                               \
  do {                                                                     \
    const _Float16* g0 = ((mat) ? gpB : gpA)[(h)*2] + (size_t)(kt)*64;     \
    const _Float16* g1 = ((mat) ? gpB : gpA)[(h)*2 + 1] + (size_t)(kt)*64; \
    _Float16* d_ = &lds[buf][mat][h][t * 8];                               \
    gload_lds16(g0, d_);                                                   \
    gload_lds16(g1, d_ + 4096);                                            \
  } while (0)

#define LDA_(buf, mh)                                             \
  _Pragma("unroll") for (int m = 0; m < 4; m++) {                 \
    a[0][m] = *(const f16x8*)(aB[buf][0] + (mh)*4096 + m * 1024); \
    a[1][m] = *(const f16x8*)(aB[buf][1] + (mh)*4096 + m * 1024); \
  }

#define LDB_(buf, nh)                                                   \
  _Pragma("unroll") for (int nf = 0; nf < 2; nf++) {                    \
    b[nh][0][nf] = *(const f16x8*)(bB[buf][0] + (nh)*2048 + nf * 1024); \
    b[nh][1][nf] = *(const f16x8*)(bB[buf][1] + (nh)*2048 + nf * 1024); \
  }

#define MM_(mh, nh)                                                        \
  __builtin_amdgcn_s_setprio(1);                                           \
  _Pragma("unroll") for (int m = 0; m < 4; m++)                            \
      _Pragma("unroll") for (int nf = 0; nf < 2; nf++)                     \
          _Pragma("unroll") for (int ks = 0; ks < 2; ks++) acc[(mh)*4 + m] \
              [(nh)*2 + nf] = __builtin_amdgcn_mfma_f32_16x16x32_f16(      \
                  a[ks][m], b[nh][ks][nf], acc[(mh)*4 + m][(nh)*2 + nf],   \
                  0, 0, 0);                                                \
  __builtin_amdgcn_s_setprio(0);

// store one output quadrant (issued right after its final MFMA)
#define STQ(mh, nh)                                                        \
  _Pragma("unroll") for (int mf = 0; mf < 4; mf++) {                       \
    size_t row0 = arow0 + wm * 128 + ((mh)*4 + mf) * 16 + lg * 4;          \
    _Pragma("unroll") for (int nf = 0; nf < 2; nf++) {                     \
      size_t col = brow0 + wn * 64 + ((nh)*2 + nf) * 16 + lr;              \
      _Pragma("unroll") for (int j = 0; j < 4; j++) {                      \
        OutT v_ = (OutT)acc[(mh)*4 + mf][(nh)*2 + nf][j];                  \
        if constexpr (NT)                                                  \
          __builtin_nontemporal_store(v_, &C[(row0 + j) * N + col]);       \
        else                                                               \
          C[(row0 + j) * N + col] = v_;                                    \
      }                                                                    \
    }                                                                      \
  }

template <typename OutT, bool NT>
__device__ __forceinline__ void gemm_body(
    const _Float16* const* gpA, const _Float16* const* gpB,
    OutT* __restrict__ C, int N, size_t arow0, size_t brow0,
    _Float16 (&lds)[2][2][2][8192]) {
  const int t = threadIdx.x;
  const int lane = t & 63, wave = t >> 6;
  const int wm = wave >> 2, wn = wave & 3;
  const int lr = lane & 15, lg = lane >> 4;

  const int cx0 = (lg * 8) ^ ((lr & 7) << 3);
  const int cx1 = cx0 ^ 32;
  const _Float16* aB[2][2];
  const _Float16* bB[2][2];
#pragma unroll
  for (int bf = 0; bf < 2; bf++) {
    aB[bf][0] = &lds[bf][0][wm][lr * 64 + cx0];
    aB[bf][1] = &lds[bf][0][wm][lr * 64 + cx1];
    bB[bf][0] = &lds[bf][1][wn >> 1][(wn & 1) * 4096 + lr * 64 + cx0];
    bB[bf][1] = &lds[bf][1][wn >> 1][(wn & 1) * 4096 + lr * 64 + cx1];
  }

  f32x4 acc[8][4] = {};
  f16x8 a[2][4], b[2][2][2];

  // ---- prologue: k0 -> buf0 (A0,A1,B0,B1); k1.B0,B1 -> buf1 ----
  STG(0, 0, 0, 0);
  STG(0, 0, 1, 0);
  STG(1, 0, 0, 0);
  STG(1, 0, 1, 0);
  STG(1, 1, 0, 1);
  STG(1, 1, 1, 1);
  VM4;  // 12 outstanding -> drain 8 oldest = all of tile 0
  BAR;

  // ---- steady loop: 7 iterations (k-tiles 0..13), full staging ----
  // ONE barrier per phase: [LD; STG; (VM)] BAR LGKM0 MM
  for (int i = 0; i < 7; i++) {
    const int k1 = 2 * i + 1, k2 = 2 * i + 2, k3 = 2 * i + 3;
    LDA_(0, 0); LDB_(0, 0); STG(0, k1, 0, 1);      BAR; LGKM0; MM_(0, 0);
    LDB_(0, 1);             STG(0, k1, 1, 1);      BAR; LGKM0; MM_(0, 1);
    LDA_(0, 1);             STG(1, k2, 0, 0);      BAR; LGKM0; MM_(1, 1);
                            STG(1, k2, 1, 0); VM4; BAR; LGKM0; MM_(1, 0);
    LDA_(1, 0); LDB_(1, 0); STG(0, k2, 0, 0);      BAR; LGKM0; MM_(0, 0);
    LDB_(1, 1);             STG(0, k2, 1, 0);      BAR; LGKM0; MM_(0, 1);
    LDA_(1, 1);             STG(1, k3, 0, 1);      BAR; LGKM0; MM_(1, 1);
                            STG(1, k3, 1, 1); VM4; BAR; LGKM0; MM_(1, 0);
  }

  // ---- peeled tail (k-tiles 14,15): stage only A(15); vmcnt(0) at P3.
  // Quadrant stores issue right after each quadrant's final MFMA.
  {
    LDA_(0, 0); LDB_(0, 0); STG(0, 15, 0, 1);      BAR; LGKM0; MM_(0, 0);
    LDB_(0, 1);             STG(0, 15, 1, 1);      BAR; LGKM0; MM_(0, 1);
    LDA_(0, 1);                                    BAR; LGKM0; MM_(1, 1);
                                              VM0; BAR; LGKM0; MM_(1, 0);
    LDA_(1, 0); LDB_(1, 0);                        BAR; LGKM0; MM_(0, 0);
    STQ(0, 0);
    LDB_(1, 1);                                    BAR; LGKM0; MM_(0, 1);
    STQ(0, 1);
    LDA_(1, 1);                                    BAR; LGKM0; MM_(1, 1);
    STQ(1, 1);
                                                        LGKM0; MM_(1, 0);
    STQ(1, 0);
  }
}

// ---- fused Q-proj (sw<256, perm-gathered A) + KV-proj (sw>=256), 512 wg ----
__global__ __launch_bounds__(512, 2) void gemm_qkv8(
    const _Float16* __restrict__ xh, const _Float16* __restrict__ wqh,
    _Float16* __restrict__ qh, _Float16* __restrict__ kvh) {
  __shared__ _Float16 lds[2][2][2][8192];
  const int t = threadIdx.x;
  const int id = blockIdx.x;
  const int sw = (id & 7) * (gridDim.x >> 3) + (id >> 3);
  const bool iskv = sw >= 256;
  const int wid = iskv ? sw - 256 : sw;
  const int N = iskv ? 2048 : 1024;
  const int bn = iskv ? (wid & 7) : (wid & 3);
  const int bm = iskv ? (wid >> 3) : (wid >> 2);
  const _Float16* Bw = wqh + (iskv ? (size_t)1048576 : 0);
  _Float16* C = iskv ? kvh : qh;

  const int sgrow = t >> 3;
  const int sgcol = ((t & 7) * 8) ^ ((sgrow & 7) << 3);
  const _Float16* gpA[4];
  const _Float16* gpB[4];
#pragma unroll
  for (int r = 0; r < 4; r++) {
    int mr = bm * 256 + 64 * r + sgrow;
    int ar = iskv ? arow_gather(mr) : qrow_gather(mr);
    gpA[r] = xh + (size_t)ar * 1024 + sgcol;
    gpB[r] = Bw + ((size_t)bn * 256 + 64 * r + sgrow) * 1024 + sgcol;
  }
  gemm_body<_Float16, false>(gpA, gpB, C, N, (size_t)bm * 256,
                             (size_t)bn * 256, lds);
}

// ---- out-proj: 16384 x 1024 x 1024, fp32 output (nontemporal) ----
__global__ __launch_bounds__(512, 2) void gemm_out8(
    const _Float16* __restrict__ atth, const _Float16* __restrict__ woh,
    float* __restrict__ out) {
  __shared__ _Float16 lds[2][2][2][8192];
  const int t = threadIdx.x;
  const int id = blockIdx.x;
  const int sw = (id & 7) * (gridDim.x >> 3) + (id >> 3);
  const int bn = sw & 3, bm = sw >> 2;

  const int sgrow = t >> 3;
  const int sgcol = ((t & 7) * 8) ^ ((sgrow & 7) << 3);
  const _Float16* gpA[4];
  const _Float16* gpB[4];
#pragma unroll
  for (int r = 0; r < 4; r++) {
    gpA[r] = atth + ((size_t)bm * 256 + 64 * r + sgrow) * 1024 + sgcol;
    gpB[r] = woh + ((size_t)bn * 256 + 64 * r + sgrow) * 1024 + sgcol;
  }
  gemm_body<float, true>(gpA, gpB, out, 1024, (size_t)bm * 256,
                         (size_t)bn * 256, lds);
}

// ----------------------------- attention -----------------------------------
// One block per (b,h,s). Q now PRE-PERMUTED in qh -> fully linear staging.
// K,V contiguous from dilation-packed kvh[b*2048 + s*64 + j][2048].
#define STRD 72

__global__ __launch_bounds__(256) void hilbert_attn(
    const _Float16* __restrict__ qh, const _Float16* __restrict__ kvh,
    _Float16* __restrict__ aout) {
  __shared__ _Float16 Qs[128 * STRD];
  __shared__ _Float16 Ks[64 * STRD];
  __shared__ _Float16 Vt[64 * STRD];  // transposed: Vt[d][j] = V[j][d]
  __shared__ _Float16 Ps[128 * STRD];
  const int blk = blockIdx.x;
  const int s = blk & 31, h = (blk >> 5) & 15, b = blk >> 9;
  const int t = threadIdx.x, lane = t & 63, wave = t >> 6;
  const int lr = lane & 15, lg = lane >> 4, lk = lg * 8;
  const int col = (t & 7) * 8, rr = t >> 3;
  const size_t qb = ((size_t)b * 4096 + s * 128) * 1024;
  const size_t kvb = ((size_t)b * 2048 + s * 64) * 2048;

#pragma unroll
  for (int i = 0; i < 4; i++) {
    int m = i * 32 + rr;
    *(f16x8*)&Qs[m * STRD + col] =
        *(const f16x8*)&qh[qb + (size_t)m * 1024 + h * 64 + col];
  }
#pragma unroll
  for (int i = 0; i < 2; i++) {
    int j = i * 32 + rr;
    *(f16x8*)&Ks[j * STRD + col] =
        *(const f16x8*)&kvh[kvb + (size_t)j * 2048 + h * 64 + col];
    f16x8 vv =
        *(const f16x8*)&kvh[kvb + (size_t)j * 2048 + 1024 + h * 64 + col];
#pragma unroll
    for (int e = 0; e < 8; e++) Vt[(col + e) * STRD + j] = vv[e];
  }
  __syncthreads();

  f32x4 accs[2][4] = {};
#pragma unroll
  for (int kk = 0; kk < 2; kk++) {
    f16x8 aa[2], bb[4];
#pragma unroll
    for (int m = 0; m < 2; m++)
      aa[m] = *(const f16x8*)&Qs[(wave * 32 + m * 16 + lr) * STRD + kk * 32 + lk];
#pragma unroll
    for (int n = 0; n < 4; n++)
      bb[n] = *(const f16x8*)&Ks[(n * 16 + lr) * STRD + kk * 32 + lk];
#pragma unroll
    for (int m = 0; m < 2; m++)
#pragma unroll
      for (int n = 0; n < 4; n++)
        accs[m][n] =
            __builtin_amdgcn_mfma_f32_16x16x32_f16(aa[m], bb[n], accs[m][n], 0, 0, 0);
  }

#pragma unroll
  for (int m = 0; m < 2; m++) {
#pragma unroll
    for (int j = 0; j < 4; j++) {
      float sc0 = accs[m][0][j] * 0.125f;
      float sc1 = accs[m][1][j] * 0.125f;
      float sc2 = accs[m][2][j] * 0.125f;
      float sc3 = accs[m][3][j] * 0.125f;
      float mx = fmaxf(fmaxf(sc0, sc1), fmaxf(sc2, sc3));
#pragma unroll
      for (int d = 1; d < 16; d <<= 1) mx = fmaxf(mx, __shfl_xor(mx, d, 16));
      float e0 = __expf(sc0 - mx), e1 = __expf(sc1 - mx);
      float e2 = __expf(sc2 - mx), e3 = __expf(sc3 - mx);
      float sum = (e0 + e1) + (e2 + e3);
#pragma unroll
      for (int d = 1; d < 16; d <<= 1) sum += __shfl_xor(sum, d, 16);
      float inv = 1.0f / sum;
      int row = wave * 32 + m * 16 + lg * 4 + j;
      Ps[row * STRD + 0 * 16 + lr] = (_Float16)(e0 * inv);
      Ps[row * STRD + 1 * 16 + lr] = (_Float16)(e1 * inv);
      Ps[row * STRD + 2 * 16 + lr] = (_Float16)(e2 * inv);
      Ps[row * STRD + 3 * 16 + lr] = (_Float16)(e3 * inv);
    }
  }
  __syncthreads();

  f32x4 acco[2][4] = {};
#pragma unroll
  for (int kk = 0; kk < 2; kk++) {
    f16x8 aa[2], bb[4];
#pragma unroll
    for (int m = 0; m < 2; m++)
      aa[m] = *(const f16x8*)&Ps[(wave * 32 + m * 16 + lr) * STRD + kk * 32 + lk];
#pragma unroll
    for (int n = 0; n < 4; n++)
      bb[n] = *(const f16x8*)&Vt[(n * 16 + lr) * STRD + kk * 32 + lk];
#pragma unroll
    for (int m = 0; m < 2; m++)
#pragma unroll
      for (int n = 0; n < 4; n++)
        acco[m][n] =
            __builtin_amdgcn_mfma_f32_16x16x32_f16(aa[m], bb[n], acco[m][n], 0, 0, 0);
  }

  const size_t orow0 = (size_t)b * 4096 + s * 128;
#pragma unroll
  for (int m = 0; m < 2; m++) {
#pragma unroll
    for (int n = 0; n < 4; n++) {
#pragma unroll
      for (int j = 0; j < 4; j++) {
        size_t row = orow0 + wave * 32 + m * 16 + lg * 4 + j;
        aout[row * 1024 + h * 64 + n * 16 + lr] = (_Float16)acco[m][n][j];
      }
    }
  }
}

// ---------------------------------------------------------------------------
extern "C" void kernel_launch(void* const* d_in, const int* in_sizes, int n_in,
                              void* d_out, int out_size, void* d_ws, size_t ws_size,
                              hipStream_t stream) {
  const float* x = (const float*)d_in[0];      // (4,4096,1024)
  const float* w_qkv = (const float*)d_in[1];  // (3072,1024)
  const float* w_out = (const float*)d_in[2];  // (1024,1024)
  float* out = (float*)d_out;                  // (4,4096,1024) fp32
  char* ws = (char*)d_ws;

  _Float16* xh = (_Float16*)(ws + 0);                    // 33,554,432 B
  _Float16* wqh = (_Float16*)(ws + (size_t)33554432);    //  6,291,456 B
  _Float16* woh = (_Float16*)(ws + (size_t)39845888);    //  2,097,152 B
  _Float16* qh = (_Float16*)(ws + (size_t)41943040);     // 33,554,432 B
  _Float16* kvh = (_Float16*)(ws + (size_t)75497472);    // 33,554,432 B
  _Float16* atth = (_Float16*)(ws + (size_t)109051904);  // 33,554,432 B

  cast_all<<<2048, 256, 0, stream>>>(x, xh, w_qkv, wqh, w_out, woh);

  // fused Q-proj (256 wg, perm-gathered) + KV-proj (256 wg, dilation-packed)
  gemm_qkv8<<<512, 512, 0, stream>>>(xh, wqh, qh, kvh);
  hilbert_attn<<<2048, 256, 0, stream>>>(qh, kvh, atth);
  gemm_out8<<<256, 512, 0, stream>>>(atth, woh, out);
}

// Round 12
// 155.187 us; speedup vs baseline: 1.0239x; 1.0239x over previous
//
#include <hip/hip_runtime.h>

// ---------------------------------------------------------------------------
// HilbertAttention: fused cast -> fused {Q-proj | dilation-packed KV-proj}
// (fp16 MFMA, 256^2 8-phase, ONE barrier per phase, SPLIT K-half waits)
// -> segmented attention -> out-proj.
// B=4, M=4096, D=1024, H=16, hd=64, SEG=128, DIL=2 -> S=32.
// perm = closed-form serpentine (g==64). Output stays in permuted row order.
// KV-GEMM computes only the even within-segment rows (DIL=2), gathered via
// per-lane gload_lds source, written dilation-packed.
// R12: per-phase reads are ordered [ks0-group, ks1-group] and the MFMA burst
// is split into two 8-MFMA halves gated by COUNTED lgkmcnt(6/4/2) then
// lgkmcnt(0) — the ks1 reads' latency hides under the ks0 MFMAs (the old
// lgkmcnt(0)+sched_barrier before all 16 MFMAs forbade this overlap).
// Cross-wave schedule (barriers, STG slots, vmcnt ledger) unchanged from R10.
// ---------------------------------------------------------------------------

typedef _Float16 f16x8 __attribute__((ext_vector_type(8)));
typedef _Float16 f16x4 __attribute__((ext_vector_type(4)));
typedef float f32x4 __attribute__((ext_vector_type(4)));

__device__ __forceinline__ int hperm(int i) {
  int r = i >> 6, c = i & 63;
  return (r << 6) | ((r & 1) ? (63 - c) : c);
}
// A'-row m' -> x-row for KV gather: m' = b*2048+s*64+j -> b*4096+hperm(s*128+2j)
__device__ __forceinline__ int arow_gather(int mp) {
  int b = mp >> 11, i = mp & 2047;
  int s = i >> 6, j = i & 63;
  return b * 4096 + hperm(s * 128 + 2 * j);
}
__device__ __forceinline__ void gload_lds16(const _Float16* g, _Float16* l) {
  __builtin_amdgcn_global_load_lds(
      (const __attribute__((address_space(1))) void*)g,
      (__attribute__((address_space(3))) void*)l, 16, 0, 0);
}

// -------------------- fused cast fp32 -> fp16 (grid-stride) ----------------
__global__ __launch_bounds__(256) void cast_all(
    const float* __restrict__ x, _Float16* __restrict__ xh,
    const float* __restrict__ wq, _Float16* __restrict__ wqh,
    const float* __restrict__ wo, _Float16* __restrict__ woh) {
  for (int i = blockIdx.x * 256 + threadIdx.x; i < 5242880; i += 256 * 2048) {
    const float* s;
    _Float16* d;
    int j;
    if (i < 4194304) {
      s = x; d = xh; j = i;
    } else if (i < 4980736) {
      s = wq; d = wqh; j = i - 4194304;
    } else {
      s = wo; d = woh; j = i - 4980736;
    }
    float4 v = ((const float4*)s)[j];
    f16x4 o;
    o[0] = (_Float16)v.x;
    o[1] = (_Float16)v.y;
    o[2] = (_Float16)v.z;
    o[3] = (_Float16)v.w;
    *(f16x4*)&d[(size_t)j * 4] = o;
  }
}

// ---------------- 256x256 8-phase NT GEMM body: C = A * B^T ----------------
// K=1024 (NK=16), BK=64, 512 thr = 8 waves (2Mx4N), per-wave 128x64 out.
// LDS 128 KiB. Swizzle: 16B-slot XOR ((row&7)<<3 halves).
// Stage slots: P0/P1 = A(k1)->buf1; P2..P5 = B,B,A,A of (k2)->buf0;
// P6/P7 = B(k3)->buf1. vmcnt(4) only at P3/P7 (counted, never 0 in loop).
// Final iteration peeled: stage only A(15); vmcnt(0) at its P3; quadrant
// stores issued right after each quadrant's final MFMA.

#define BAR __builtin_amdgcn_s_barrier()
#define LGKM_(n)                                            \
  do {                                                      \
    asm volatile("s_waitcnt lgkmcnt(" #n ")" ::: "memory"); \
    __builtin_amdgcn_sched_barrier(0);                      \
  } while (0)
#define VM4 asm volatile("s_waitcnt vmcnt(4)" ::: "memory")
#define VM0 asm volatile("s_waitcnt vmcnt(0)" ::: "memory")

#define STG(mat, kt, h, buf)                                               \
  do {                                                                     \
    const _Float16* g0 = ((mat) ? gpB : gpA)[(h)*2] + (size_t)(kt)*64;     \
    const _Float16* g1 = ((mat) ? gpB : gpA)[(h)*2 + 1] + (size_t)(kt)*64; \
    _Float16* d_ = &lds[buf][mat][h][t * 8];                               \
    gload_lds16(g0, d_);                                                   \
    gload_lds16(g1, d_ + 4096);                                            \
  } while (0)

// frag reads split by K-half ks (4 A-reads / 2 B-reads each)
#define LDA_K(buf, mh, ks)                                     \
  _Pragma("unroll") for (int m = 0; m < 4; m++) a[ks][m] =     \
      *(const f16x8*)(aB[buf][ks] + (mh)*4096 + m * 1024);

#define LDB_K(buf, nh, ks)                                           \
  _Pragma("unroll") for (int nf = 0; nf < 2; nf++) b[nh][ks][nf] =   \
      *(const f16x8*)(bB[buf][ks] + (nh)*2048 + nf * 1024);

// one K-half MFMA burst: 8 independent MFMAs (distinct accumulators)
#define MMH(mh, nh, ks)                                                     \
  __builtin_amdgcn_s_setprio(1);                                            \
  _Pragma("unroll") for (int m = 0; m < 4; m++)                             \
      _Pragma("unroll") for (int nf = 0; nf < 2; nf++)                      \
          acc[(mh)*4 + m][(nh)*2 + nf] =                                    \
              __builtin_amdgcn_mfma_f32_16x16x32_f16(                       \
                  a[ks][m], b[nh][ks][nf], acc[(mh)*4 + m][(nh)*2 + nf],    \
                  0, 0, 0);                                                 \
  __builtin_amdgcn_s_setprio(0);

// store one output quadrant (issued right after its final MFMA)
#define STQ(mh, nh)                                                        \
  _Pragma("unroll") for (int mf = 0; mf < 4; mf++) {                       \
    size_t row0 = arow0 + wm * 128 + ((mh)*4 + mf) * 16 + lg * 4;          \
    _Pragma("unroll") for (int nf = 0; nf < 2; nf++) {                     \
      size_t col = brow0 + wn * 64 + ((nh)*2 + nf) * 16 + lr;              \
      _Pragma("unroll") for (int j = 0; j < 4; j++) {                      \
        OutT v_ = (OutT)acc[(mh)*4 + mf][(nh)*2 + nf][j];                  \
        if constexpr (NT)                                                  \
          __builtin_nontemporal_store(v_, &C[(row0 + j) * N + col]);       \
        else                                                               \
          C[(row0 + j) * N + col] = v_;                                    \
      }                                                                    \
    }                                                                      \
  }

template <typename OutT, bool NT>
__device__ __forceinline__ void gemm_body(
    const _Float16* const* gpA, const _Float16* const* gpB,
    OutT* __restrict__ C, int N, size_t arow0, size_t brow0,
    _Float16 (&lds)[2][2][2][8192]) {
  const int t = threadIdx.x;
  const int lane = t & 63, wave = t >> 6;
  const int wm = wave >> 2, wn = wave & 3;
  const int lr = lane & 15, lg = lane >> 4;

  const int cx0 = (lg * 8) ^ ((lr & 7) << 3);
  const int cx1 = cx0 ^ 32;
  const _Float16* aB[2][2];
  const _Float16* bB[2][2];
#pragma unroll
  for (int bf = 0; bf < 2; bf++) {
    aB[bf][0] = &lds[bf][0][wm][lr * 64 + cx0];
    aB[bf][1] = &lds[bf][0][wm][lr * 64 + cx1];
    bB[bf][0] = &lds[bf][1][wn >> 1][(wn & 1) * 4096 + lr * 64 + cx0];
    bB[bf][1] = &lds[bf][1][wn >> 1][(wn & 1) * 4096 + lr * 64 + cx1];
  }

  f32x4 acc[8][4] = {};
  f16x8 a[2][4], b[2][2][2];

  // ---- prologue: k0 -> buf0 (A0,A1,B0,B1); k1.B0,B1 -> buf1 ----
  STG(0, 0, 0, 0);
  STG(0, 0, 1, 0);
  STG(1, 0, 0, 0);
  STG(1, 0, 1, 0);
  STG(1, 1, 0, 1);
  STG(1, 1, 1, 1);
  VM4;  // 12 outstanding -> drain 8 oldest = all of tile 0
  BAR;

  // ---- steady loop: 7 iterations (k-tiles 0..13), full staging ----
  // Phase = [reads(ks0,ks1); STG; (VM)] BAR; LGKM(n); 8xMFMA; LGKM(0); 8xMFMA
  for (int i = 0; i < 7; i++) {
    const int k1 = 2 * i + 1, k2 = 2 * i + 2, k3 = 2 * i + 3;
    // P0
    LDA_K(0, 0, 0); LDB_K(0, 0, 0); LDA_K(0, 0, 1); LDB_K(0, 0, 1);
    STG(0, k1, 0, 1); BAR; LGKM_(6); MMH(0, 0, 0); LGKM_(0); MMH(0, 0, 1);
    // P1
    LDB_K(0, 1, 0); LDB_K(0, 1, 1);
    STG(0, k1, 1, 1); BAR; LGKM_(2); MMH(0, 1, 0); LGKM_(0); MMH(0, 1, 1);
    // P2
    LDA_K(0, 1, 0); LDA_K(0, 1, 1);
    STG(1, k2, 0, 0); BAR; LGKM_(4); MMH(1, 1, 0); LGKM_(0); MMH(1, 1, 1);
    // P3 (no reads; operands already drained in P2)
    STG(1, k2, 1, 0); VM4; BAR; MMH(1, 0, 0); MMH(1, 0, 1);
    // P4
    LDA_K(1, 0, 0); LDB_K(1, 0, 0); LDA_K(1, 0, 1); LDB_K(1, 0, 1);
    STG(0, k2, 0, 0); BAR; LGKM_(6); MMH(0, 0, 0); LGKM_(0); MMH(0, 0, 1);
    // P5
    LDB_K(1, 1, 0); LDB_K(1, 1, 1);
    STG(0, k2, 1, 0); BAR; LGKM_(2); MMH(0, 1, 0); LGKM_(0); MMH(0, 1, 1);
    // P6
    LDA_K(1, 1, 0); LDA_K(1, 1, 1);
    STG(1, k3, 0, 1); BAR; LGKM_(4); MMH(1, 1, 0); LGKM_(0); MMH(1, 1, 1);
    // P7
    STG(1, k3, 1, 1); VM4; BAR; MMH(1, 0, 0); MMH(1, 0, 1);
  }

  // ---- peeled tail (k-tiles 14,15): stage only A(15); vmcnt(0) at P3.
  // Quadrant stores issue right after each quadrant's final MFMA.
  {
    LDA_K(0, 0, 0); LDB_K(0, 0, 0); LDA_K(0, 0, 1); LDB_K(0, 0, 1);
    STG(0, 15, 0, 1); BAR; LGKM_(6); MMH(0, 0, 0); LGKM_(0); MMH(0, 0, 1);
    LDB_K(0, 1, 0); LDB_K(0, 1, 1);
    STG(0, 15, 1, 1); BAR; LGKM_(2); MMH(0, 1, 0); LGKM_(0); MMH(0, 1, 1);
    LDA_K(0, 1, 0); LDA_K(0, 1, 1);
    BAR; LGKM_(4); MMH(1, 1, 0); LGKM_(0); MMH(1, 1, 1);
    VM0; BAR; MMH(1, 0, 0); MMH(1, 0, 1);
    LDA_K(1, 0, 0); LDB_K(1, 0, 0); LDA_K(1, 0, 1); LDB_K(1, 0, 1);
    BAR; LGKM_(6); MMH(0, 0, 0); LGKM_(0); MMH(0, 0, 1);
    STQ(0, 0);
    LDB_K(1, 1, 0); LDB_K(1, 1, 1);
    BAR; LGKM_(2); MMH(0, 1, 0); LGKM_(0); MMH(0, 1, 1);
    STQ(0, 1);
    LDA_K(1, 1, 0); LDA_K(1, 1, 1);
    BAR; LGKM_(4); MMH(1, 1, 0); LGKM_(0); MMH(1, 1, 1);
    STQ(1, 1);
    MMH(1, 0, 0); MMH(1, 0, 1);
    STQ(1, 0);
  }
}

// ---- fused Q-proj (sw<256) + KV-proj (sw>=256) over a 512-wg grid ----
__global__ __launch_bounds__(512, 2) void gemm_qkv8(
    const _Float16* __restrict__ xh, const _Float16* __restrict__ wqh,
    _Float16* __restrict__ qh, _Float16* __restrict__ kvh) {
  __shared__ _Float16 lds[2][2][2][8192];
  const int t = threadIdx.x;
  const int id = blockIdx.x;
  const int sw = (id & 7) * (gridDim.x >> 3) + (id >> 3);
  const bool iskv = sw >= 256;
  const int wid = iskv ? sw - 256 : sw;
  const int N = iskv ? 2048 : 1024;
  const int bn = iskv ? (wid & 7) : (wid & 3);
  const int bm = iskv ? (wid >> 3) : (wid >> 2);
  const _Float16* Bw = wqh + (iskv ? (size_t)1048576 : 0);
  _Float16* C = iskv ? kvh : qh;

  const int sgrow = t >> 3;
  const int sgcol = ((t & 7) * 8) ^ ((sgrow & 7) << 3);
  const _Float16* gpA[4];
  const _Float16* gpB[4];
#pragma unroll
  for (int r = 0; r < 4; r++) {
    int mr = bm * 256 + 64 * r + sgrow;
    int ar = iskv ? arow_gather(mr) : mr;
    gpA[r] = xh + (size_t)ar * 1024 + sgcol;
    gpB[r] = Bw + ((size_t)bn * 256 + 64 * r + sgrow) * 1024 + sgcol;
  }
  gemm_body<_Float16, false>(gpA, gpB, C, N, (size_t)bm * 256,
                             (size_t)bn * 256, lds);
}

// ---- out-proj: 16384 x 1024 x 1024, fp32 output (nontemporal) ----
__global__ __launch_bounds__(512, 2) void gemm_out8(
    const _Float16* __restrict__ atth, const _Float16* __restrict__ woh,
    float* __restrict__ out) {
  __shared__ _Float16 lds[2][2][2][8192];
  const int t = threadIdx.x;
  const int id = blockIdx.x;
  const int sw = (id & 7) * (gridDim.x >> 3) + (id >> 3);
  const int bn = sw & 3, bm = sw >> 2;

  const int sgrow = t >> 3;
  const int sgcol = ((t & 7) * 8) ^ ((sgrow & 7) << 3);
  const _Float16* gpA[4];
  const _Float16* gpB[4];
#pragma unroll
  for (int r = 0; r < 4; r++) {
    gpA[r] = atth + ((size_t)bm * 256 + 64 * r + sgrow) * 1024 + sgcol;
    gpB[r] = woh + ((size_t)bn * 256 + 64 * r + sgrow) * 1024 + sgcol;
  }
  gemm_body<float, true>(gpA, gpB, out, 1024, (size_t)bm * 256,
                         (size_t)bn * 256, lds);
}

// ----------------------------- attention -----------------------------------
// One block per (b,h,s). Q gathered from qh via perm; K,V read CONTIGUOUSLY
// from the dilation-packed kvh[b*2048 + s*64 + j][2048].
#define STRD 72

__global__ __launch_bounds__(256) void hilbert_attn(
    const _Float16* __restrict__ qh, const _Float16* __restrict__ kvh,
    _Float16* __restrict__ aout) {
  __shared__ _Float16 Qs[128 * STRD];
  __shared__ _Float16 Ks[64 * STRD];
  __shared__ _Float16 Vt[64 * STRD];  // transposed: Vt[d][j] = V[j][d]
  __shared__ _Float16 Ps[128 * STRD];
  const int blk = blockIdx.x;
  const int s = blk & 31, h = (blk >> 5) & 15, b = blk >> 9;
  const int t = threadIdx.x, lane = t & 63, wave = t >> 6;
  const int lr = lane & 15, lg = lane >> 4, lk = lg * 8;
  const int col = (t & 7) * 8, rr = t >> 3;
  const size_t kvb = ((size_t)b * 2048 + s * 64) * 2048;

#pragma unroll
  for (int i = 0; i < 4; i++) {
    int m = i * 32 + rr;
    int p = b * 4096 + hperm(s * 128 + m);
    *(f16x8*)&Qs[m * STRD + col] =
        *(const f16x8*)&qh[(size_t)p * 1024 + h * 64 + col];
  }
#pragma unroll
  for (int i = 0; i < 2; i++) {
    int j = i * 32 + rr;
    *(f16x8*)&Ks[j * STRD + col] =
        *(const f16x8*)&kvh[kvb + (size_t)j * 2048 + h * 64 + col];
    f16x8 vv =
        *(const f16x8*)&kvh[kvb + (size_t)j * 2048 + 1024 + h * 64 + col];
#pragma unroll
    for (int e = 0; e < 8; e++) Vt[(col + e) * STRD + j] = vv[e];
  }
  __syncthreads();

  f32x4 accs[2][4] = {};
#pragma unroll
  for (int kk = 0; kk < 2; kk++) {
    f16x8 aa[2], bb[4];
#pragma unroll
    for (int m = 0; m < 2; m++)
      aa[m] = *(const f16x8*)&Qs[(wave * 32 + m * 16 + lr) * STRD + kk * 32 + lk];
#pragma unroll
    for (int n = 0; n < 4; n++)
      bb[n] = *(const f16x8*)&Ks[(n * 16 + lr) * STRD + kk * 32 + lk];
#pragma unroll
    for (int m = 0; m < 2; m++)
#pragma unroll
      for (int n = 0; n < 4; n++)
        accs[m][n] =
            __builtin_amdgcn_mfma_f32_16x16x32_f16(aa[m], bb[n], accs[m][n], 0, 0, 0);
  }

#pragma unroll
  for (int m = 0; m < 2; m++) {
#pragma unroll
    for (int j = 0; j < 4; j++) {
      float sc0 = accs[m][0][j] * 0.125f;
      float sc1 = accs[m][1][j] * 0.125f;
      float sc2 = accs[m][2][j] * 0.125f;
      float sc3 = accs[m][3][j] * 0.125f;
      float mx = fmaxf(fmaxf(sc0, sc1), fmaxf(sc2, sc3));
#pragma unroll
      for (int d = 1; d < 16; d <<= 1) mx = fmaxf(mx, __shfl_xor(mx, d, 16));
      float e0 = __expf(sc0 - mx), e1 = __expf(sc1 - mx);
      float e2 = __expf(sc2 - mx), e3 = __expf(sc3 - mx);
      float sum = (e0 + e1) + (e2 + e3);
#pragma unroll
      for (int d = 1; d < 16; d <<= 1) sum += __shfl_xor(sum, d, 16);
      float inv = 1.0f / sum;
      int row = wave * 32 + m * 16 + lg * 4 + j;
      Ps[row * STRD + 0 * 16 + lr] = (_Float16)(e0 * inv);
      Ps[row * STRD + 1 * 16 + lr] = (_Float16)(e1 * inv);
      Ps[row * STRD + 2 * 16 + lr] = (_Float16)(e2 * inv);
      Ps[row * STRD + 3 * 16 + lr] = (_Float16)(e3 * inv);
    }
  }
  __syncthreads();

  f32x4 acco[2][4] = {};
#pragma unroll
  for (int kk = 0; kk < 2; kk++) {
    f16x8 aa[2], bb[4];
#pragma unroll
    for (int m = 0; m < 2; m++)
      aa[m] = *(const f16x8*)&Ps[(wave * 32 + m * 16 + lr) * STRD + kk * 32 + lk];
#pragma unroll
    for (int n = 0; n < 4; n++)
      bb[n] = *(const f16x8*)&Vt[(n * 16 + lr) * STRD + kk * 32 + lk];
#pragma unroll
    for (int m = 0; m < 2; m++)
#pragma unroll
      for (int n = 0; n < 4; n++)
        acco[m][n] =
            __builtin_amdgcn_mfma_f32_16x16x32_f16(aa[m], bb[n], acco[m][n], 0, 0, 0);
  }

  const size_t orow0 = (size_t)b * 4096 + s * 128;
#pragma unroll
  for (int m = 0; m < 2; m++) {
#pragma unroll
    for (int n = 0; n < 4; n++) {
#pragma unroll
      for (int j = 0; j < 4; j++) {
        size_t row = orow0 + wave * 32 + m * 16 + lg * 4 + j;
        aout[row * 1024 + h * 64 + n * 16 + lr] = (_Float16)acco[m][n][j];
      }
    }
  }
}

// ---------------------------------------------------------------------------
extern "C" void kernel_launch(void* const* d_in, const int* in_sizes, int n_in,
                              void* d_out, int out_size, void* d_ws, size_t ws_size,
                              hipStream_t stream) {
  const float* x = (const float*)d_in[0];      // (4,4096,1024)
  const float* w_qkv = (const float*)d_in[1];  // (3072,1024)
  const float* w_out = (const float*)d_in[2];  // (1024,1024)
  float* out = (float*)d_out;                  // (4,4096,1024) fp32
  char* ws = (char*)d_ws;

  _Float16* xh = (_Float16*)(ws + 0);                    // 33,554,432 B
  _Float16* wqh = (_Float16*)(ws + (size_t)33554432);    //  6,291,456 B
  _Float16* woh = (_Float16*)(ws + (size_t)39845888);    //  2,097,152 B
  _Float16* qh = (_Float16*)(ws + (size_t)41943040);     // 33,554,432 B
  _Float16* kvh = (_Float16*)(ws + (size_t)75497472);    // 33,554,432 B
  _Float16* atth = (_Float16*)(ws + (size_t)109051904);  // 33,554,432 B

  cast_all<<<2048, 256, 0, stream>>>(x, xh, w_qkv, wqh, w_out, woh);

  // fused Q-proj (256 wg) + KV-proj (256 wg)
  gemm_qkv8<<<512, 512, 0, stream>>>(xh, wqh, qh, kvh);
  hilbert_attn<<<2048, 256, 0, stream>>>(qh, kvh, atth);
  gemm_out8<<<256, 512, 0, stream>>>(atth, woh, out);
}

// Round 13
// 153.884 us; speedup vs baseline: 1.0325x; 1.0085x over previous
//
#include <hip/hip_runtime.h>

// ---------------------------------------------------------------------------
// HilbertAttention: fused cast -> fused {Q-proj | dilation-packed KV-proj}
// (fp16 MFMA, 256^2 8-phase, ONE barrier per phase, SPLIT K-half waits)
// -> segmented attention -> out-proj.
// B=4, M=4096, D=1024, H=16, hd=64, SEG=128, DIL=2 -> S=32.
// perm = closed-form serpentine (g==64). Output stays in permuted row order.
// KV-GEMM computes only the even within-segment rows (DIL=2), gathered via
// per-lane gload_lds source, written dilation-packed.
// R13: s_setprio removed — all 8 waves run identical phase code in lockstep
// (single barrier/phase), so prio arbitration is a no-op with overhead
// (T5 null-to-negative on lockstep schedules, m190).
// ---------------------------------------------------------------------------

typedef _Float16 f16x8 __attribute__((ext_vector_type(8)));
typedef _Float16 f16x4 __attribute__((ext_vector_type(4)));
typedef float f32x4 __attribute__((ext_vector_type(4)));

__device__ __forceinline__ int hperm(int i) {
  int r = i >> 6, c = i & 63;
  return (r << 6) | ((r & 1) ? (63 - c) : c);
}
// A'-row m' -> x-row for KV gather: m' = b*2048+s*64+j -> b*4096+hperm(s*128+2j)
__device__ __forceinline__ int arow_gather(int mp) {
  int b = mp >> 11, i = mp & 2047;
  int s = i >> 6, j = i & 63;
  return b * 4096 + hperm(s * 128 + 2 * j);
}
__device__ __forceinline__ void gload_lds16(const _Float16* g, _Float16* l) {
  __builtin_amdgcn_global_load_lds(
      (const __attribute__((address_space(1))) void*)g,
      (__attribute__((address_space(3))) void*)l, 16, 0, 0);
}

// -------------------- fused cast fp32 -> fp16 (grid-stride) ----------------
__global__ __launch_bounds__(256) void cast_all(
    const float* __restrict__ x, _Float16* __restrict__ xh,
    const float* __restrict__ wq, _Float16* __restrict__ wqh,
    const float* __restrict__ wo, _Float16* __restrict__ woh) {
  for (int i = blockIdx.x * 256 + threadIdx.x; i < 5242880; i += 256 * 2048) {
    const float* s;
    _Float16* d;
    int j;
    if (i < 4194304) {
      s = x; d = xh; j = i;
    } else if (i < 4980736) {
      s = wq; d = wqh; j = i - 4194304;
    } else {
      s = wo; d = woh; j = i - 4980736;
    }
    float4 v = ((const float4*)s)[j];
    f16x4 o;
    o[0] = (_Float16)v.x;
    o[1] = (_Float16)v.y;
    o[2] = (_Float16)v.z;
    o[3] = (_Float16)v.w;
    *(f16x4*)&d[(size_t)j * 4] = o;
  }
}

// ---------------- 256x256 8-phase NT GEMM body: C = A * B^T ----------------
// K=1024 (NK=16), BK=64, 512 thr = 8 waves (2Mx4N), per-wave 128x64 out.
// LDS 128 KiB. Swizzle: 16B-slot XOR ((row&7)<<3 halves).
// Stage slots: P0/P1 = A(k1)->buf1; P2..P5 = B,B,A,A of (k2)->buf0;
// P6/P7 = B(k3)->buf1. vmcnt(4) only at P3/P7 (counted, never 0 in loop).
// Final iteration peeled: stage only A(15); vmcnt(0) at its P3; quadrant
// stores issued right after each quadrant's final MFMA.

#define BAR __builtin_amdgcn_s_barrier()
#define LGKM_(n)                                            \
  do {                                                      \
    asm volatile("s_waitcnt lgkmcnt(" #n ")" ::: "memory"); \
    __builtin_amdgcn_sched_barrier(0);                      \
  } while (0)
#define VM4 asm volatile("s_waitcnt vmcnt(4)" ::: "memory")
#define VM0 asm volatile("s_waitcnt vmcnt(0)" ::: "memory")

#define STG(mat, kt, h, buf)                                               \
  do {                                                                     \
    const _Float16* g0 = ((mat) ? gpB : gpA)[(h)*2] + (size_t)(kt)*64;     \
    const _Float16* g1 = ((mat) ? gpB : gpA)[(h)*2 + 1] + (size_t)(kt)*64; \
    _Float16* d_ = &lds[buf][mat][h][t * 8];                               \
    gload_lds16(g0, d_);                                                   \
    gload_lds16(g1, d_ + 4096);                                            \
  } while (0)

// frag reads split by K-half ks (4 A-reads / 2 B-reads each)
#define LDA_K(buf, mh, ks)                                     \
  _Pragma("unroll") for (int m = 0; m < 4; m++) a[ks][m] =     \
      *(const f16x8*)(aB[buf][ks] + (mh)*4096 + m * 1024);

#define LDB_K(buf, nh, ks)                                           \
  _Pragma("unroll") for (int nf = 0; nf < 2; nf++) b[nh][ks][nf] =   \
      *(const f16x8*)(bB[buf][ks] + (nh)*2048 + nf * 1024);

// one K-half MFMA burst: 8 independent MFMAs (distinct accumulators)
#define MMH(mh, nh, ks)                                                     \
  _Pragma("unroll") for (int m = 0; m < 4; m++)                             \
      _Pragma("unroll") for (int nf = 0; nf < 2; nf++)                      \
          acc[(mh)*4 + m][(nh)*2 + nf] =                                    \
              __builtin_amdgcn_mfma_f32_16x16x32_f16(                       \
                  a[ks][m], b[nh][ks][nf], acc[(mh)*4 + m][(nh)*2 + nf],    \
                  0, 0, 0);

// store one output quadrant (issued right after its final MFMA)
#define STQ(mh, nh)                                                        \
  _Pragma("unroll") for (int mf = 0; mf < 4; mf++) {                       \
    size_t row0 = arow0 + wm * 128 + ((mh)*4 + mf) * 16 + lg * 4;          \
    _Pragma("unroll") for (int nf = 0; nf < 2; nf++) {                     \
      size_t col = brow0 + wn * 64 + ((nh)*2 + nf) * 16 + lr;              \
      _Pragma("unroll") for (int j = 0; j < 4; j++) {                      \
        OutT v_ = (OutT)acc[(mh)*4 + mf][(nh)*2 + nf][j];                  \
        if constexpr (NT)                                                  \
          __builtin_nontemporal_store(v_, &C[(row0 + j) * N + col]);       \
        else                                                               \
          C[(row0 + j) * N + col] = v_;                                    \
      }                                                                    \
    }                                                                      \
  }

template <typename OutT, bool NT>
__device__ __forceinline__ void gemm_body(
    const _Float16* const* gpA, const _Float16* const* gpB,
    OutT* __restrict__ C, int N, size_t arow0, size_t brow0,
    _Float16 (&lds)[2][2][2][8192]) {
  const int t = threadIdx.x;
  const int lane = t & 63, wave = t >> 6;
  const int wm = wave >> 2, wn = wave & 3;
  const int lr = lane & 15, lg = lane >> 4;

  const int cx0 = (lg * 8) ^ ((lr & 7) << 3);
  const int cx1 = cx0 ^ 32;
  const _Float16* aB[2][2];
  const _Float16* bB[2][2];
#pragma unroll
  for (int bf = 0; bf < 2; bf++) {
    aB[bf][0] = &lds[bf][0][wm][lr * 64 + cx0];
    aB[bf][1] = &lds[bf][0][wm][lr * 64 + cx1];
    bB[bf][0] = &lds[bf][1][wn >> 1][(wn & 1) * 4096 + lr * 64 + cx0];
    bB[bf][1] = &lds[bf][1][wn >> 1][(wn & 1) * 4096 + lr * 64 + cx1];
  }

  f32x4 acc[8][4] = {};
  f16x8 a[2][4], b[2][2][2];

  // ---- prologue: k0 -> buf0 (A0,A1,B0,B1); k1.B0,B1 -> buf1 ----
  STG(0, 0, 0, 0);
  STG(0, 0, 1, 0);
  STG(1, 0, 0, 0);
  STG(1, 0, 1, 0);
  STG(1, 1, 0, 1);
  STG(1, 1, 1, 1);
  VM4;  // 12 outstanding -> drain 8 oldest = all of tile 0
  BAR;

  // ---- steady loop: 7 iterations (k-tiles 0..13), full staging ----
  // Phase = [reads(ks0,ks1); STG; (VM)] BAR; LGKM(n); 8xMFMA; LGKM(0); 8xMFMA
  for (int i = 0; i < 7; i++) {
    const int k1 = 2 * i + 1, k2 = 2 * i + 2, k3 = 2 * i + 3;
    // P0
    LDA_K(0, 0, 0); LDB_K(0, 0, 0); LDA_K(0, 0, 1); LDB_K(0, 0, 1);
    STG(0, k1, 0, 1); BAR; LGKM_(6); MMH(0, 0, 0); LGKM_(0); MMH(0, 0, 1);
    // P1
    LDB_K(0, 1, 0); LDB_K(0, 1, 1);
    STG(0, k1, 1, 1); BAR; LGKM_(2); MMH(0, 1, 0); LGKM_(0); MMH(0, 1, 1);
    // P2
    LDA_K(0, 1, 0); LDA_K(0, 1, 1);
    STG(1, k2, 0, 0); BAR; LGKM_(4); MMH(1, 1, 0); LGKM_(0); MMH(1, 1, 1);
    // P3 (no reads; operands already drained in P2)
    STG(1, k2, 1, 0); VM4; BAR; MMH(1, 0, 0); MMH(1, 0, 1);
    // P4
    LDA_K(1, 0, 0); LDB_K(1, 0, 0); LDA_K(1, 0, 1); LDB_K(1, 0, 1);
    STG(0, k2, 0, 0); BAR; LGKM_(6); MMH(0, 0, 0); LGKM_(0); MMH(0, 0, 1);
    // P5
    LDB_K(1, 1, 0); LDB_K(1, 1, 1);
    STG(0, k2, 1, 0); BAR; LGKM_(2); MMH(0, 1, 0); LGKM_(0); MMH(0, 1, 1);
    // P6
    LDA_K(1, 1, 0); LDA_K(1, 1, 1);
    STG(1, k3, 0, 1); BAR; LGKM_(4); MMH(1, 1, 0); LGKM_(0); MMH(1, 1, 1);
    // P7
    STG(1, k3, 1, 1); VM4; BAR; MMH(1, 0, 0); MMH(1, 0, 1);
  }

  // ---- peeled tail (k-tiles 14,15): stage only A(15); vmcnt(0) at P3.
  // Quadrant stores issue right after each quadrant's final MFMA.
  {
    LDA_K(0, 0, 0); LDB_K(0, 0, 0); LDA_K(0, 0, 1); LDB_K(0, 0, 1);
    STG(0, 15, 0, 1); BAR; LGKM_(6); MMH(0, 0, 0); LGKM_(0); MMH(0, 0, 1);
    LDB_K(0, 1, 0); LDB_K(0, 1, 1);
    STG(0, 15, 1, 1); BAR; LGKM_(2); MMH(0, 1, 0); LGKM_(0); MMH(0, 1, 1);
    LDA_K(0, 1, 0); LDA_K(0, 1, 1);
    BAR; LGKM_(4); MMH(1, 1, 0); LGKM_(0); MMH(1, 1, 1);
    VM0; BAR; MMH(1, 0, 0); MMH(1, 0, 1);
    LDA_K(1, 0, 0); LDB_K(1, 0, 0); LDA_K(1, 0, 1); LDB_K(1, 0, 1);
    BAR; LGKM_(6); MMH(0, 0, 0); LGKM_(0); MMH(0, 0, 1);
    STQ(0, 0);
    LDB_K(1, 1, 0); LDB_K(1, 1, 1);
    BAR; LGKM_(2); MMH(0, 1, 0); LGKM_(0); MMH(0, 1, 1);
    STQ(0, 1);
    LDA_K(1, 1, 0); LDA_K(1, 1, 1);
    BAR; LGKM_(4); MMH(1, 1, 0); LGKM_(0); MMH(1, 1, 1);
    STQ(1, 1);
    MMH(1, 0, 0); MMH(1, 0, 1);
    STQ(1, 0);
  }
}

// ---- fused Q-proj (sw<256) + KV-proj (sw>=256) over a 512-wg grid ----
__global__ __launch_bounds__(512, 2) void gemm_qkv8(
    const _Float16* __restrict__ xh, const _Float16* __restrict__ wqh,
    _Float16* __restrict__ qh, _Float16* __restrict__ kvh) {
  __shared__ _Float16 lds[2][2][2][8192];
  const int t = threadIdx.x;
  const int id = blockIdx.x;
  const int sw = (id & 7) * (gridDim.x >> 3) + (id >> 3);
  const bool iskv = sw >= 256;
  const int wid = iskv ? sw - 256 : sw;
  const int N = iskv ? 2048 : 1024;
  const int bn = iskv ? (wid & 7) : (wid & 3);
  const int bm = iskv ? (wid >> 3) : (wid >> 2);
  const _Float16* Bw = wqh + (iskv ? (size_t)1048576 : 0);
  _Float16* C = iskv ? kvh : qh;

  const int sgrow = t >> 3;
  const int sgcol = ((t & 7) * 8) ^ ((sgrow & 7) << 3);
  const _Float16* gpA[4];
  const _Float16* gpB[4];
#pragma unroll
  for (int r = 0; r < 4; r++) {
    int mr = bm * 256 + 64 * r + sgrow;
    int ar = iskv ? arow_gather(mr) : mr;
    gpA[r] = xh + (size_t)ar * 1024 + sgcol;
    gpB[r] = Bw + ((size_t)bn * 256 + 64 * r + sgrow) * 1024 + sgcol;
  }
  gemm_body<_Float16, false>(gpA, gpB, C, N, (size_t)bm * 256,
                             (size_t)bn * 256, lds);
}

// ---- out-proj: 16384 x 1024 x 1024, fp32 output (nontemporal) ----
__global__ __launch_bounds__(512, 2) void gemm_out8(
    const _Float16* __restrict__ atth, const _Float16* __restrict__ woh,
    float* __restrict__ out) {
  __shared__ _Float16 lds[2][2][2][8192];
  const int t = threadIdx.x;
  const int id = blockIdx.x;
  const int sw = (id & 7) * (gridDim.x >> 3) + (id >> 3);
  const int bn = sw & 3, bm = sw >> 2;

  const int sgrow = t >> 3;
  const int sgcol = ((t & 7) * 8) ^ ((sgrow & 7) << 3);
  const _Float16* gpA[4];
  const _Float16* gpB[4];
#pragma unroll
  for (int r = 0; r < 4; r++) {
    gpA[r] = atth + ((size_t)bm * 256 + 64 * r + sgrow) * 1024 + sgcol;
    gpB[r] = woh + ((size_t)bn * 256 + 64 * r + sgrow) * 1024 + sgcol;
  }
  gemm_body<float, true>(gpA, gpB, out, 1024, (size_t)bm * 256,
                         (size_t)bn * 256, lds);
}

// ----------------------------- attention -----------------------------------
// One block per (b,h,s). Q gathered from qh via perm; K,V read CONTIGUOUSLY
// from the dilation-packed kvh[b*2048 + s*64 + j][2048].
#define STRD 72

__global__ __launch_bounds__(256) void hilbert_attn(
    const _Float16* __restrict__ qh, const _Float16* __restrict__ kvh,
    _Float16* __restrict__ aout) {
  __shared__ _Float16 Qs[128 * STRD];
  __shared__ _Float16 Ks[64 * STRD];
  __shared__ _Float16 Vt[64 * STRD];  // transposed: Vt[d][j] = V[j][d]
  __shared__ _Float16 Ps[128 * STRD];
  const int blk = blockIdx.x;
  const int s = blk & 31, h = (blk >> 5) & 15, b = blk >> 9;
  const int t = threadIdx.x, lane = t & 63, wave = t >> 6;
  const int lr = lane & 15, lg = lane >> 4, lk = lg * 8;
  const int col = (t & 7) * 8, rr = t >> 3;
  const size_t kvb = ((size_t)b * 2048 + s * 64) * 2048;

#pragma unroll
  for (int i = 0; i < 4; i++) {
    int m = i * 32 + rr;
    int p = b * 4096 + hperm(s * 128 + m);
    *(f16x8*)&Qs[m * STRD + col] =
        *(const f16x8*)&qh[(size_t)p * 1024 + h * 64 + col];
  }
#pragma unroll
  for (int i = 0; i < 2; i++) {
    int j = i * 32 + rr;
    *(f16x8*)&Ks[j * STRD + col] =
        *(const f16x8*)&kvh[kvb + (size_t)j * 2048 + h * 64 + col];
    f16x8 vv =
        *(const f16x8*)&kvh[kvb + (size_t)j * 2048 + 1024 + h * 64 + col];
#pragma unroll
    for (int e = 0; e < 8; e++) Vt[(col + e) * STRD + j] = vv[e];
  }
  __syncthreads();

  f32x4 accs[2][4] = {};
#pragma unroll
  for (int kk = 0; kk < 2; kk++) {
    f16x8 aa[2], bb[4];
#pragma unroll
    for (int m = 0; m < 2; m++)
      aa[m] = *(const f16x8*)&Qs[(wave * 32 + m * 16 + lr) * STRD + kk * 32 + lk];
#pragma unroll
    for (int n = 0; n < 4; n++)
      bb[n] = *(const f16x8*)&Ks[(n * 16 + lr) * STRD + kk * 32 + lk];
#pragma unroll
    for (int m = 0; m < 2; m++)
#pragma unroll
      for (int n = 0; n < 4; n++)
        accs[m][n] =
            __builtin_amdgcn_mfma_f32_16x16x32_f16(aa[m], bb[n], accs[m][n], 0, 0, 0);
  }

#pragma unroll
  for (int m = 0; m < 2; m++) {
#pragma unroll
    for (int j = 0; j < 4; j++) {
      float sc0 = accs[m][0][j] * 0.125f;
      float sc1 = accs[m][1][j] * 0.125f;
      float sc2 = accs[m][2][j] * 0.125f;
      float sc3 = accs[m][3][j] * 0.125f;
      float mx = fmaxf(fmaxf(sc0, sc1), fmaxf(sc2, sc3));
#pragma unroll
      for (int d = 1; d < 16; d <<= 1) mx = fmaxf(mx, __shfl_xor(mx, d, 16));
      float e0 = __expf(sc0 - mx), e1 = __expf(sc1 - mx);
      float e2 = __expf(sc2 - mx), e3 = __expf(sc3 - mx);
      float sum = (e0 + e1) + (e2 + e3);
#pragma unroll
      for (int d = 1; d < 16; d <<= 1) sum += __shfl_xor(sum, d, 16);
      float inv = 1.0f / sum;
      int row = wave * 32 + m * 16 + lg * 4 + j;
      Ps[row * STRD + 0 * 16 + lr] = (_Float16)(e0 * inv);
      Ps[row * STRD + 1 * 16 + lr] = (_Float16)(e1 * inv);
      Ps[row * STRD + 2 * 16 + lr] = (_Float16)(e2 * inv);
      Ps[row * STRD + 3 * 16 + lr] = (_Float16)(e3 * inv);
    }
  }
  __syncthreads();

  f32x4 acco[2][4] = {};
#pragma unroll
  for (int kk = 0; kk < 2; kk++) {
    f16x8 aa[2], bb[4];
#pragma unroll
    for (int m = 0; m < 2; m++)
      aa[m] = *(const f16x8*)&Ps[(wave * 32 + m * 16 + lr) * STRD + kk * 32 + lk];
#pragma unroll
    for (int n = 0; n < 4; n++)
      bb[n] = *(const f16x8*)&Vt[(n * 16 + lr) * STRD + kk * 32 + lk];
#pragma unroll
    for (int m = 0; m < 2; m++)
#pragma unroll
      for (int n = 0; n < 4; n++)
        acco[m][n] =
            __builtin_amdgcn_mfma_f32_16x16x32_f16(aa[m], bb[n], acco[m][n], 0, 0, 0);
  }

  const size_t orow0 = (size_t)b * 4096 + s * 128;
#pragma unroll
  for (int m = 0; m < 2; m++) {
#pragma unroll
    for (int n = 0; n < 4; n++) {
#pragma unroll
      for (int j = 0; j < 4; j++) {
        size_t row = orow0 + wave * 32 + m * 16 + lg * 4 + j;
        aout[row * 1024 + h * 64 + n * 16 + lr] = (_Float16)acco[m][n][j];
      }
    }
  }
}

// ---------------------------------------------------------------------------
extern "C" void kernel_launch(void* const* d_in, const int* in_sizes, int n_in,
                              void* d_out, int out_size, void* d_ws, size_t ws_size,
                              hipStream_t stream) {
  const float* x = (const float*)d_in[0];      // (4,4096,1024)
  const float* w_qkv = (const float*)d_in[1];  // (3072,1024)
  const float* w_out = (const float*)d_in[2];  // (1024,1024)
  float* out = (float*)d_out;                  // (4,4096,1024) fp32
  char* ws = (char*)d_ws;

  _Float16* xh = (_Float16*)(ws + 0);                    // 33,554,432 B
  _Float16* wqh = (_Float16*)(ws + (size_t)33554432);    //  6,291,456 B
  _Float16* woh = (_Float16*)(ws + (size_t)39845888);    //  2,097,152 B
  _Float16* qh = (_Float16*)(ws + (size_t)41943040);     // 33,554,432 B
  _Float16* kvh = (_Float16*)(ws + (size_t)75497472);    // 33,554,432 B
  _Float16* atth = (_Float16*)(ws + (size_t)109051904);  // 33,554,432 B

  cast_all<<<2048, 256, 0, stream>>>(x, xh, w_qkv, wqh, w_out, woh);

  // fused Q-proj (256 wg) + KV-proj (256 wg)
  gemm_qkv8<<<512, 512, 0, stream>>>(xh, wqh, qh, kvh);
  hilbert_attn<<<2048, 256, 0, stream>>>(qh, kvh, atth);
  gemm_out8<<<256, 512, 0, stream>>>(atth, woh, out);
}